// Round 11
// baseline (119.919 us; speedup 1.0000x reference)
//
#include <hip/hip_runtime.h>

// Elman RNN, T=2e6, I=2, H=30, O=1 — fully-folded MFMA chunked scan.
// r16 (2nd resubmit — r9/r10 benches never acquired a GPU):
// 32x32 MFMA shape — 32 chunks/wave-step (was 16).
// r15 post-mortem: LUT tanh (trans->LDS gather) HURT +3.8us => trans is
// cheap on gfx950; revert to r14 exp2/rcp tanh. Model: cost/wave-step =
// F (fixed: 2 MFMA pipe + hazards + store + loop) + 8E (per-element);
// F:E split unknown. This round: halve wave-steps by doubling chunks
// per wave via v_mfma_f32_32x32x16_f16 (K=32 via 2 chained x16 MFMAs).
// Wins if F>~34 cyc; also measures F directly.
// Layout (inferred, analog of HW-verified 16x16x32 split): A/B halves
// 0-3: k=4*(lane>>5)+i, halves 4-7: k=8+4*(lane>>5)+i. C/D: col=lane&31,
// row=(reg&3)+8*(reg>>2)+4*(lane>>5) [m74/m101]. Self-aligned: D reg r
// IS the h-row B half r needs -> th[0..7]->B_lo, th[8..15]->B_hi.
// x-insert: lanes>=32, bhi.u2[3] (rows 30,31). out = d[14] (row 30).
//   Wpad = [SC*W_hh | SC*W_ih ; W_fc 0 ; 0] (32x32), split A_lo=k0..15,
//   A_hi=k16..31; C = [SC*(b_ih+b_hh); b_fc; 0] row-mapped.
// tanh(p) = 1 - 2*rcp(1 + exp2(SC*p)), SC = 2*log2(e).
// Geometry: 512 blocks x 128 thr (2 waves) x 32 chunks = 32768 >= 31250;
// 1 wave/SIMD, CHUNK_LEN=64, burn 16 (windows 0-1).

#define T_LEN     2000000
#define HID       30
#define CHUNK_LEN 64
#define BURN      15           // burn iters = 16 (windows 0-1)
#define NBLOCK    512
#define WSTEPS    8
#define NWIN      10           // 2 burn + 8 main

typedef __attribute__((ext_vector_type(8)))  _Float16 half8;
typedef __attribute__((ext_vector_type(2)))  __fp16   fp16x2;
typedef __attribute__((ext_vector_type(16))) float    f32x16;

union h8u { half8 v8; fp16x2 v2[4]; unsigned u2[4]; };
union h2u { fp16x2 v; unsigned u; };

// issue next window's x loads into nxt[] (all lanes; lane l and l+32 dup
// addresses -> coalesced/broadcast; clamp keeps every lane in bounds).
#define PREFETCH(O) {                                                        \
    _Pragma("unroll")                                                        \
    for (int s = 0; s < WSTEPS; ++s) {                                       \
        int tt = wbase + (O) * WSTEPS + s;                                   \
        tt = tt < 0 ? 0 : (tt >= T_LEN ? T_LEN - 1 : tt);                    \
        nxt[s] = xf2[tt];                                                    \
    }                                                                        \
}

// convert the landed window to packed f16 pairs
#define CONVERT() {                                                          \
    _Pragma("unroll")                                                        \
    for (int s = 0; s < WSTEPS; ++s) {                                       \
        h2u c; c.v = __builtin_amdgcn_cvt_pkrtz(nxt[s].x, nxt[s].y);         \
        xcur[s] = c.u;                                                       \
    }                                                                        \
}

// one chain-step; x value comes in as a register (XC)
#define STEP_BODY(XC, MASKQ, STOREQ)                                         \
{                                                                            \
    float th[16];                                                            \
    _Pragma("unroll")                                                        \
    for (int i = 0; i < 16; ++i)                                             \
        th[i] = 1.f - 2.f * __builtin_amdgcn_rcpf(1.f + __builtin_amdgcn_exp2f(d[i])); \
    if (MASKQ) {                                                             \
        const float m = (t_cur >= 1) ? 1.f : 0.f;                            \
        _Pragma("unroll")                                                    \
        for (int i = 0; i < 16; ++i) th[i] *= m;                             \
    }                                                                        \
    h8u blo, bhi;                                                            \
    blo.v2[0] = __builtin_amdgcn_cvt_pkrtz(th[0],  th[1]);                   \
    blo.v2[1] = __builtin_amdgcn_cvt_pkrtz(th[2],  th[3]);                   \
    blo.v2[2] = __builtin_amdgcn_cvt_pkrtz(th[4],  th[5]);                   \
    blo.v2[3] = __builtin_amdgcn_cvt_pkrtz(th[6],  th[7]);                   \
    bhi.v2[0] = __builtin_amdgcn_cvt_pkrtz(th[8],  th[9]);                   \
    bhi.v2[1] = __builtin_amdgcn_cvt_pkrtz(th[10], th[11]);                  \
    bhi.v2[2] = __builtin_amdgcn_cvt_pkrtz(th[12], th[13]);                  \
    bhi.v2[3] = __builtin_amdgcn_cvt_pkrtz(th[14], th[15]);                  \
    if (hs1) bhi.u2[3] = (XC);                                               \
    f32x16 tmp = __builtin_amdgcn_mfma_f32_32x32x16_f16(a_lo.v8, blo.v8, cC, 0, 0, 0); \
    d = __builtin_amdgcn_mfma_f32_32x32x16_f16(a_hi.v8, bhi.v8, tmp, 0, 0, 0); \
    if (STOREQ) {                                                            \
        const int ta = t_cur - 1;                                            \
        if (hs1 && ta < my_end) out[ta] = d[14];                             \
    }                                                                        \
    ++t_cur;                                                                 \
}

__global__ __launch_bounds__(128, 1)
void rnn_mfma_kernel(const float* __restrict__ x,
                     const float* __restrict__ W_ih,
                     const float* __restrict__ W_hh,
                     const float* __restrict__ b_ih,
                     const float* __restrict__ b_hh,
                     const float* __restrict__ W_fc,
                     const float* __restrict__ b_fc,
                     float* __restrict__ out)
{
    const int tid  = threadIdx.x;
    const int wave = tid >> 6;          // 0..1
    const int lane = tid & 63;
    const int col  = lane & 31;         // chunk column / A row
    const int hg   = lane >> 5;         // K half-group 0..1
    const bool hs1 = (hg == 1);

    const int chunk = blockIdx.x * 64 + wave * 32 + col;  // global chunk
    const int wbase = chunk * CHUNK_LEN - BURN;           // first x time
    const float2* __restrict__ xf2 = (const float2*)x;

    const float SC = 2.0f * 1.44269504088896340736f;   // 2*log2(e)

    // padded 32x32 weight element (row r, col k), SC folded into rows 0-29
    auto wval = [&](int r, int k) -> float {
        if (r < HID)  return SC * (k < HID ? W_hh[r*HID + k] : W_ih[r*2 + (k - HID)]);
        if (r == HID) return (k < HID) ? W_fc[k] : 0.f;   // FC row, unscaled
        return 0.f;                                        // row 31: zero
    };

    // ---- static A fragments: A_lo = k 0..15, A_hi = k 16..31;
    //      halves 0-3: k=4*hg+i, halves 4-7: k=8+4*hg+i (split layout) ----
    h8u a_lo, a_hi;
#pragma unroll
    for (int i = 0; i < 4; ++i) {
        a_lo.v8[i]   = (_Float16)wval(col,      4*hg + i);
        a_lo.v8[4+i] = (_Float16)wval(col,  8 + 4*hg + i);
        a_hi.v8[i]   = (_Float16)wval(col, 16 + 4*hg + i);
        a_hi.v8[4+i] = (_Float16)wval(col, 24 + 4*hg + i);
    }

    // ---- C operand: row-mapped biases; row30 = b_fc; row31 = 0 ----
    f32x16 cC;
#pragma unroll
    for (int r = 0; r < 16; ++r) {
        const int row = (r & 3) + 8*(r >> 2) + 4*hg;
        cC[r] = (row < HID)  ? SC * (b_ih[row] + b_hh[row])
              : (row == HID) ? b_fc[0] : 0.f;
    }

    int my_end = chunk * CHUNK_LEN + CHUNK_LEN;
    if (my_end > T_LEN) my_end = T_LEN;

    __builtin_amdgcn_sched_barrier(0);

    f32x16 d = {0.f,0.f,0.f,0.f,0.f,0.f,0.f,0.f,
                0.f,0.f,0.f,0.f,0.f,0.f,0.f,0.f};

    int t_cur = wbase;                  // time of x consumed this step

    float2   nxt[WSTEPS];               // in-flight window (float2)
    unsigned xcur[WSTEPS];              // current window (packed f16 pairs)

    PREFETCH(0)

    // ---- burn windows 0-1 (16 steps, h masked while t_cur < 1) ----
#pragma clang loop unroll(disable)
    for (int o = 0; o < 2; ++o) {
        CONVERT()
        PREFETCH(o + 1)
#pragma unroll
        for (int s = 0; s < WSTEPS; ++s) {
            STEP_BODY(xcur[s], true, false)
        }
    }

    // ---- main windows 2-9 (64 steps, store out[t_cur-1]) ----
#pragma clang loop unroll(disable)
    for (int o = 2; o < NWIN; ++o) {
        CONVERT()
        if (o < NWIN - 1) { PREFETCH(o + 1) }
#pragma unroll
        for (int s = 0; s < WSTEPS; ++s) {
            STEP_BODY(xcur[s], false, true)
        }
    }
}

extern "C" void kernel_launch(void* const* d_in, const int* in_sizes, int n_in,
                              void* d_out, int out_size, void* d_ws, size_t ws_size,
                              hipStream_t stream)
{
    const float* x    = (const float*)d_in[0];
    const float* W_ih = (const float*)d_in[1];
    const float* W_hh = (const float*)d_in[2];
    const float* b_ih = (const float*)d_in[3];
    const float* b_hh = (const float*)d_in[4];
    const float* W_fc = (const float*)d_in[5];
    const float* b_fc = (const float*)d_in[6];
    float* out = (float*)d_out;

    // 512 blocks x 2 waves x 32 chunks = 32768 chunks (>= 31250);
    // 2 blocks/CU = 1 wave/SIMD; no LDS.
    rnn_mfma_kernel<<<NBLOCK, 128, 0, stream>>>(x, W_ih, W_hh, b_ih, b_hh,
                                                W_fc, b_fc, out);
}

// Round 12
// 99.368 us; speedup vs baseline: 1.2068x; 1.2068x over previous
//
#include <hip/hip_runtime.h>

// Elman RNN, T=2e6, I=2, H=30, O=1 — fully-folded MFMA chunked scan.
// r17: revert r16 (32x32 @ 1 wave/SIMD = latency-exposed disaster: 54us
// kernel, MfmaUtil 3.6%, VALUBusy 33%, occ 7.4% — measured) back to r14
// (16x16x32, 2 waves/SIMD, ~20us kernel), PLUS float4-batched output
// stores: accumulate d_b[2] into obuf[s&3], store dwordx4 every 4th
// step. 64 -> 16 stores/chain: 4x less vmcnt pressure (stores count
// vmcnt; window-boundary waits may drain store ACKS, a candidate for
// the unexplained ~110 cyc/wave-step), better store shape, less addr
// VALU. T%64==0 => per-chunk stores all-or-nothing (chunk < 31250).
// Per chain-step one padded 32x32 matvec via 2x mfma_f32_16x16x32_f16
// (HW-confirmed split frag layout: halves 0-3 k=4g+i, 4-7 k=16+4g+i):
//   A = [SC*W_hh | SC*W_ih ; W_fc 0 ; 0], B rows 0-29 = h_{t-1} (f16),
//   rows 30,31 = x_t; C = [SC*(b_ih+b_hh); b_fc; 0]
// => D rows 0-29 = SC*pre_t, row 30 = out[t-1] (g3 lanes' d_b[2]).
// SC = 2*log2(e): tanh(p) = 1 - 2*rcp(1 + exp2(SC*p)).

#define T_LEN     2000000
#define HID       30
#define CHUNK_LEN 64
#define BURN      15           // burn iters = 16 (windows 0-1)
#define NBLOCK    512          // 512 blk x 64 chunks = 32768 >= 31250
#define WSTEPS    8
#define NWIN      10           // 2 burn + 8 main
#define NCHUNK_ST 31250        // chunks < this store (T/CHUNK_LEN)

typedef __attribute__((ext_vector_type(8))) _Float16 half8;
typedef __attribute__((ext_vector_type(2))) __fp16   fp16x2;  // pkrtz type
typedef __attribute__((ext_vector_type(4))) float    float4v;

union h8u { half8 v8; fp16x2 v2[4]; unsigned u2[4]; };
union h2u { fp16x2 v; unsigned u; };

// issue next window's x loads into nxt[] (all lanes; same-cl lanes dup
// addresses -> coalesced/broadcast; clamp keeps every lane in bounds).
#define PREFETCH(O) {                                                        \
    _Pragma("unroll")                                                        \
    for (int s = 0; s < WSTEPS; ++s) {                                       \
        int tt = wbase + (O) * WSTEPS + s;                                   \
        tt = tt < 0 ? 0 : (tt >= T_LEN ? T_LEN - 1 : tt);                    \
        nxt[s] = xf2[tt];                                                    \
    }                                                                        \
}

// convert the landed window to packed f16 pairs
#define CONVERT() {                                                          \
    _Pragma("unroll")                                                        \
    for (int s = 0; s < WSTEPS; ++s) {                                       \
        h2u c; c.v = __builtin_amdgcn_cvt_pkrtz(nxt[s].x, nxt[s].y);         \
        xcur[s] = c.u;                                                       \
    }                                                                        \
}

// one chain-step; x in XC; S = compile-time step index within window;
// main windows accumulate out-vals and store dwordx4 every 4th step.
#define STEP_BODY(XC, S, MASKQ, STOREQ)                                      \
{                                                                            \
    float th[8];                                                             \
    _Pragma("unroll")                                                        \
    for (int i = 0; i < 4; ++i) {                                            \
        th[i]   = 1.f - 2.f * __builtin_amdgcn_rcpf(1.f + __builtin_amdgcn_exp2f(d_t[i])); \
        th[4+i] = 1.f - 2.f * __builtin_amdgcn_rcpf(1.f + __builtin_amdgcn_exp2f(d_b[i])); \
    }                                                                        \
    if (MASKQ) {                                                             \
        const float m = (t_cur >= 1) ? 1.f : 0.f;                            \
        _Pragma("unroll")                                                    \
        for (int i = 0; i < 8; ++i) th[i] *= m;                              \
    }                                                                        \
    h8u b;                                                                   \
    b.v2[0] = __builtin_amdgcn_cvt_pkrtz(th[0], th[1]);                      \
    b.v2[1] = __builtin_amdgcn_cvt_pkrtz(th[2], th[3]);                      \
    b.v2[2] = __builtin_amdgcn_cvt_pkrtz(th[4], th[5]);                      \
    b.v2[3] = __builtin_amdgcn_cvt_pkrtz(th[6], th[7]);                      \
    if (g3) b.u2[3] = (XC);                                                  \
    d_t = __builtin_amdgcn_mfma_f32_16x16x32_f16(a_t.v8, b.v8, cT, 0, 0, 0); \
    d_b = __builtin_amdgcn_mfma_f32_16x16x32_f16(a_b.v8, b.v8, cB, 0, 0, 0); \
    if (STOREQ) {                                                            \
        obuf[(S) & 3] = d_b[2];                                              \
        if (((S) & 3) == 3 && st_ok) {                                       \
            *(float4v*)(optr + (o - 2) * WSTEPS + (S) - 3) = obuf;           \
        }                                                                    \
    }                                                                        \
    ++t_cur;                                                                 \
}

__global__ __launch_bounds__(256, 2)
void rnn_mfma_kernel(const float* __restrict__ x,
                     const float* __restrict__ W_ih,
                     const float* __restrict__ W_hh,
                     const float* __restrict__ b_ih,
                     const float* __restrict__ b_hh,
                     const float* __restrict__ W_fc,
                     const float* __restrict__ b_fc,
                     float* __restrict__ out)
{
    const int tid  = threadIdx.x;
    const int wave = tid >> 6;          // 0..3
    const int lane = tid & 63;
    const int g    = lane >> 4;         // reg-group 0..3
    const int cl   = lane & 15;         // A-row (top) / chunk column
    const bool g3  = (g == 3);

    const int chunk = blockIdx.x * 64 + wave * 16 + cl;  // global chunk
    const int wbase = chunk * CHUNK_LEN - BURN;          // first x time
    const float2* __restrict__ xf2 = (const float2*)x;

    const float SC = 2.0f * 1.44269504088896340736f;   // 2*log2(e)

    // ---- static A fragments (f16): halves 0-3 = k0 (k=4g+i),
    //      halves 4-7 = k1 (k=16+4g+i) — x32 split frag layout ----
    h8u a_t, a_b;
#pragma unroll
    for (int i = 0; i < 4; ++i) {
        const int k0 = 4*g + i;        // 0..15
        const int k1 = 16 + 4*g + i;   // 16..31
        const int mt = cl;             // rows 0..15
        const int mb = 16 + cl;        // rows 16..31

        a_t.v8[i] = (_Float16)(SC * W_hh[mt*HID + k0]);
        float v_t1;
        if (k1 < HID)        v_t1 = SC * W_hh[mt*HID + k1];
        else if (k1 == HID)  v_t1 = SC * W_ih[mt*2 + 0];
        else                 v_t1 = SC * W_ih[mt*2 + 1];
        a_t.v8[4+i] = (_Float16)v_t1;

        float v_b0, v_b1;
        if (mb < HID) {
            v_b0 = SC * W_hh[mb*HID + k0];
            if (k1 < HID)        v_b1 = SC * W_hh[mb*HID + k1];
            else if (k1 == HID)  v_b1 = SC * W_ih[mb*2 + 0];
            else                 v_b1 = SC * W_ih[mb*2 + 1];
        } else if (mb == HID) {        // FC row: unscaled, x-cols zero
            v_b0 = W_fc[k0];
            v_b1 = (k1 < HID) ? W_fc[k1] : 0.f;
        } else {                       // row 31: zero
            v_b0 = 0.f; v_b1 = 0.f;
        }
        a_b.v8[i]   = (_Float16)v_b0;
        a_b.v8[4+i] = (_Float16)v_b1;
    }

    // ---- C operands: scaled biases; row30 = b_fc; row31 = 0 ----
    float4v cT, cB;
#pragma unroll
    for (int i = 0; i < 4; ++i) {
        const int rt  = 4*g + i;
        const int rb2 = 16 + 4*g + i;
        cT[i] = SC * (b_ih[rt] + b_hh[rt]);
        cB[i] = (rb2 < HID)  ? SC * (b_ih[rb2] + b_hh[rb2])
              : (rb2 == HID) ? b_fc[0] : 0.f;
    }

    // store role: T%64==0 -> chunks < NCHUNK_ST store all 64, others none
    const bool st_ok = g3 && (chunk < NCHUNK_ST);
    float* const optr = out + chunk * CHUNK_LEN;

    __builtin_amdgcn_sched_barrier(0);

    float4v d_t = {0.f,0.f,0.f,0.f}, d_b = {0.f,0.f,0.f,0.f};
    float4v obuf;

    int t_cur = wbase;                  // time of x consumed this step

    float2   nxt[WSTEPS];               // in-flight window (float2)
    unsigned xcur[WSTEPS];              // current window (packed f16 pairs)

    PREFETCH(0)

    // ---- burn windows 0-1 (16 steps, h masked while t_cur < 1) ----
#pragma clang loop unroll(disable)
    for (int o = 0; o < 2; ++o) {
        CONVERT()
        PREFETCH(o + 1)
#pragma unroll
        for (int s = 0; s < WSTEPS; ++s) {
            STEP_BODY(xcur[s], s, true, false)
        }
    }

    // ---- main windows 2-9 (64 steps, batched dwordx4 stores) ----
#pragma clang loop unroll(disable)
    for (int o = 2; o < NWIN; ++o) {
        CONVERT()
        if (o < NWIN - 1) { PREFETCH(o + 1) }
#pragma unroll
        for (int s = 0; s < WSTEPS; ++s) {
            STEP_BODY(xcur[s], s, false, true)
        }
    }
}

extern "C" void kernel_launch(void* const* d_in, const int* in_sizes, int n_in,
                              void* d_out, int out_size, void* d_ws, size_t ws_size,
                              hipStream_t stream)
{
    const float* x    = (const float*)d_in[0];
    const float* W_ih = (const float*)d_in[1];
    const float* W_hh = (const float*)d_in[2];
    const float* b_ih = (const float*)d_in[3];
    const float* b_hh = (const float*)d_in[4];
    const float* W_fc = (const float*)d_in[5];
    const float* b_fc = (const float*)d_in[6];
    float* out = (float*)d_out;

    // 512 blocks x 4 waves x 16 chunks = 32768 chunks (>= 31250);
    // 2 blocks/CU = 2 waves/SIMD; no LDS, no intra-block coupling.
    rnn_mfma_kernel<<<NBLOCK, 256, 0, stream>>>(x, W_ih, W_hh, b_ih, b_hh,
                                                W_fc, b_fc, out);
}